// Round 19
// baseline (1023.877 us; speedup 1.0000x reference)
//
#include <hip/hip_runtime.h>
#include <math.h>

// LSTMLightweight on MI355X (R19 = R14's wave program + forced 4 waves/SIMD).
//   x[B,T,1] -> linear_in(1->16)+ReLU -> LSTM0(16) -> LSTM1(16) -> fc(16->8)+ReLU -> fc(8->1)
// R18 falsified the trans-issue model (removing v_exp/v_rcp regressed 202->323:
// longer FMA chains, same stalls). True model: with 64-thread blocks the HW
// spreads 512 waves over 1024 SIMDs -> 1 wave/SIMD; ~55% of each step is
// un-hidable dependency stall (MFMA acc-read hazards, trans latency, pack
// chains). R19 packs 16 INDEPENDENT waves (each its own 16 elements, no
// barriers in the loop) into one 1024-thread block -> 1 block/CU -> 4 waves
// per SIMD: stalls of one wave are filled by its SIMD-mates; the SIMD becomes
// issue-bound (~900 cyc/step amortized).
// Per-wave math is byte-identical to R14 (absmax 2e-3): K-permuted A-frags so
// B is lane-local (k=8g+i -> W_ih[.][4g+i] | W_hh[.][4g+i-4]; D row =
// 4*(lane>>4)+q, col=lane&15), split-bf16 3-product MFMA, bias in C-init,
// L1(t) || L0(t+1) software pipeline inside the wave.

#define L2E 1.4426950408889634f
#define WPB 16        // waves per block
#define EPB (WPB * 16)  // elements per block = 256

typedef short bf16x8 __attribute__((ext_vector_type(8)));
typedef float f32x4  __attribute__((ext_vector_type(4)));
typedef int   i32x4  __attribute__((ext_vector_type(4)));

__device__ __forceinline__ float sigm(float v) {
    return __builtin_amdgcn_rcpf(1.0f + __builtin_amdgcn_exp2f(-L2E * v));
}
__device__ __forceinline__ float tanh_(float v) {
    // tanh(v) = 1 - 2/(exp(2v)+1); saturates correctly at +-inf
    return 1.0f - 2.0f * __builtin_amdgcn_rcpf(1.0f + __builtin_amdgcn_exp2f((2.0f * L2E) * v));
}
// bf16 split helpers (truncation split: hi = top 16 bits; lo = bf16(v - hi))
__device__ __forceinline__ float hif(float a) {
    return __uint_as_float(__float_as_uint(a) & 0xFFFF0000u);
}
__device__ __forceinline__ unsigned pk2hi(float a, float b) {
    return (__float_as_uint(a) >> 16) | (__float_as_uint(b) & 0xFFFF0000u);
}
__device__ __forceinline__ unsigned pk2lo(float a, float b) {
    const float ra = a - hif(a), rb = b - hif(b);
    return (__float_as_uint(ra) >> 16) | (__float_as_uint(rb) & 0xFFFF0000u);
}
__device__ __forceinline__ short bhi(float a) { return (short)(__float_as_uint(a) >> 16); }
__device__ __forceinline__ bf16x8 mkfrag(unsigned w0, unsigned w1, unsigned w2, unsigned w3) {
    i32x4 t = {(int)w0, (int)w1, (int)w2, (int)w3};
    return __builtin_bit_cast(bf16x8, t);
}

// one layer's gate MFMAs: acc[m] = bias[m] + split-bf16(A)·B
#define GATES(ACC, AHI, ALO, BIAS, BH, BL)                                             \
    _Pragma("unroll")                                                                  \
    for (int m = 0; m < 4; ++m) {                                                      \
        ACC[m] = BIAS[m];                                                              \
        ACC[m] = __builtin_amdgcn_mfma_f32_16x16x32_bf16(ALO[m], BH, ACC[m], 0, 0, 0); \
        ACC[m] = __builtin_amdgcn_mfma_f32_16x16x32_bf16(AHI[m], BL, ACC[m], 0, 0, 0); \
        ACC[m] = __builtin_amdgcn_mfma_f32_16x16x32_bf16(AHI[m], BH, ACC[m], 0, 0, 0); \
    }

// combine: i,f,g,o -> c,h (per q); writes HV[4] and updates CC[4]
#define COMBINE(ACC, CC, HV)                                                           \
    _Pragma("unroll")                                                                  \
    for (int q = 0; q < 4; ++q) {                                                      \
        const float ig_ = sigm(ACC[0][q]);                                             \
        const float fg_ = sigm(ACC[1][q]);                                             \
        const float gv_ = tanh_(ACC[2][q]);                                            \
        const float og_ = sigm(ACC[3][q]);                                             \
        CC[q] = fmaf(fg_, CC[q], ig_ * gv_);                                           \
        HV[q] = og_ * tanh_(CC[q]);                                                    \
    }

__global__ __launch_bounds__(WPB * 64) void lstm_pack(
    const float* __restrict__ x,
    const float* __restrict__ w_in, const float* __restrict__ b_in,
    const float* __restrict__ w_ih0, const float* __restrict__ w_hh0,
    const float* __restrict__ b_ih0, const float* __restrict__ b_hh0,
    const float* __restrict__ w_ih1, const float* __restrict__ w_hh1,
    const float* __restrict__ b_ih1, const float* __restrict__ b_hh1,
    const float* __restrict__ fc_h_w, const float* __restrict__ fc_h_b,
    const float* __restrict__ fc_o_w, const float* __restrict__ fc_o_b,
    float* __restrict__ out, int B, int T)
{
    const int tid  = threadIdx.x;
    const int wid  = tid >> 6;           // wave id in block (0..WPB-1)
    const int lane = tid & 63;
    const int e    = lane & 15;          // element column (= A row within tile)
    const int g    = lane >> 4;          // k-group / D-row group
    const int base = blockIdx.x * EPB + wid * 16;    // this wave's 16 elements
    int rowe = base + e; if (rowe >= B) rowe = B - 1;

    __shared__ float htab[EPB][16];      // head exchange only (16 KB)

    // ---- A-fragments, K-permuted, split bf16 (MFMA operands: AGPR-free) ----
    bf16x8 a0hi[4], a0lo[4], a1hi[4], a1lo[4];
    f32x4  bias0[4], bias1[4];
    #pragma unroll
    for (int m = 0; m < 4; ++m) {
        const int r = 16 * m + e;
        #pragma unroll
        for (int i = 0; i < 8; ++i) {
            const float w0 = (i < 4) ? w_ih0[r * 16 + 4 * g + i]
                                     : w_hh0[r * 16 + 4 * g + (i - 4)];
            const float w1 = (i < 4) ? w_ih1[r * 16 + 4 * g + i]
                                     : w_hh1[r * 16 + 4 * g + (i - 4)];
            a0hi[m][i] = bhi(w0);  a0lo[m][i] = bhi(w0 - hif(w0));
            a1hi[m][i] = bhi(w1);  a1lo[m][i] = bhi(w1 - hif(w1));
        }
        const int rd = 16 * m + 4 * g;
        #pragma unroll
        for (int q = 0; q < 4; ++q) {
            bias0[m][q] = b_ih0[rd + q] + b_hh0[rd + q];
            bias1[m][q] = b_ih1[rd + q] + b_hh1[rd + q];
        }
    }
    float winq[4], binq[4];
    #pragma unroll
    for (int q = 0; q < 4; ++q) { winq[q] = w_in[4 * g + q]; binq[q] = b_in[4 * g + q]; }

    // ---- state ----
    float c0[4] = {0.f, 0.f, 0.f, 0.f};
    float c1[4] = {0.f, 0.f, 0.f, 0.f};
    float h1v[4] = {0.f, 0.f, 0.f, 0.f};
    unsigned h0h0, h0h1, h0l0, h0l1;                 // h0(t) packs
    unsigned h1h0 = 0u, h1h1 = 0u, h1l0 = 0u, h1l1 = 0u;   // h1(t-1) packs

    const float* xrow = x + (size_t)rowe * T;

    // ---- prologue: L0 at t=0 (h0_{-1}=0) ----
    {
        const float xv = xrow[0];
        float xq[4];
        #pragma unroll
        for (int q = 0; q < 4; ++q) xq[q] = fmaxf(fmaf(xv, winq[q], binq[q]), 0.0f);
        const bf16x8 Bh = mkfrag(pk2hi(xq[0], xq[1]), pk2hi(xq[2], xq[3]), 0u, 0u);
        const bf16x8 Bl = mkfrag(pk2lo(xq[0], xq[1]), pk2lo(xq[2], xq[3]), 0u, 0u);
        f32x4 acc[4];
        GATES(acc, a0hi, a0lo, bias0, Bh, Bl);
        float h0v[4];
        COMBINE(acc, c0, h0v);
        h0h0 = pk2hi(h0v[0], h0v[1]); h0h1 = pk2hi(h0v[2], h0v[3]);
        h0l0 = pk2lo(h0v[0], h0v[1]); h0l1 = pk2lo(h0v[2], h0v[3]);
    }

    float xv1 = xrow[(T > 1) ? 1 : 0];               // x(t+1) for the loop

    // ---- steady state: iteration t does L1(t) || L0(t+1) (independent) ----
    for (int t = 0; t < T - 1; ++t) {
        const int tn = (t + 2 < T) ? (t + 2) : (T - 1);
        const float xn = xrow[tn];                   // prefetch x(t+2)

        float xq[4];
        #pragma unroll
        for (int q = 0; q < 4; ++q) xq[q] = fmaxf(fmaf(xv1, winq[q], binq[q]), 0.0f);

        const bf16x8 B0h = mkfrag(pk2hi(xq[0], xq[1]), pk2hi(xq[2], xq[3]), h0h0, h0h1);
        const bf16x8 B0l = mkfrag(pk2lo(xq[0], xq[1]), pk2lo(xq[2], xq[3]), h0l0, h0l1);
        const bf16x8 B1h = mkfrag(h0h0, h0h1, h1h0, h1h1);
        const bf16x8 B1l = mkfrag(h0l0, h0l1, h1l0, h1l1);

        f32x4 acc0[4], acc1[4];
        GATES(acc0, a0hi, a0lo, bias0, B0h, B0l);    // L0(t+1)
        GATES(acc1, a1hi, a1lo, bias1, B1h, B1l);    // L1(t)

        float h0v[4];
        COMBINE(acc0, c0, h0v);                      // h0(t+1)
        COMBINE(acc1, c1, h1v);                      // h1(t)

        h0h0 = pk2hi(h0v[0], h0v[1]); h0h1 = pk2hi(h0v[2], h0v[3]);
        h0l0 = pk2lo(h0v[0], h0v[1]); h0l1 = pk2lo(h0v[2], h0v[3]);
        h1h0 = pk2hi(h1v[0], h1v[1]); h1h1 = pk2hi(h1v[2], h1v[3]);
        h1l0 = pk2lo(h1v[0], h1v[1]); h1l1 = pk2lo(h1v[2], h1v[3]);
        xv1 = xn;
    }

    // ---- epilogue: L1(T-1) from h0(T-1), h1(T-2) ----
    {
        const bf16x8 Bh = mkfrag(h0h0, h0h1, h1h0, h1h1);
        const bf16x8 Bl = mkfrag(h0l0, h0l1, h1l0, h1l1);
        f32x4 acc[4];
        GATES(acc, a1hi, a1lo, bias1, Bh, Bl);
        COMBINE(acc, c1, h1v);                       // final h1
    }

    // ---- head: fc_h (16->8) + ReLU, fc_o (8->1) ----
    *(float4*)&htab[wid * 16 + e][4 * g] =
        make_float4(h1v[0], h1v[1], h1v[2], h1v[3]);
    __syncthreads();
    if (tid < EPB) {
        const int ee = tid;
        float hv[16];
        #pragma unroll
        for (int k = 0; k < 16; ++k) hv[k] = htab[ee][k];
        float z[8];
        #pragma unroll
        for (int p = 0; p < 8; ++p) {
            float acc = fc_h_b[p];
            #pragma unroll
            for (int k = 0; k < 16; ++k) acc = fmaf(fc_h_w[p * 16 + k], hv[k], acc);
            z[p] = fmaxf(acc, 0.0f);
        }
        float o = fc_o_b[0];
        #pragma unroll
        for (int p = 0; p < 8; ++p) o = fmaf(fc_o_w[p], z[p], o);
        const int oe = blockIdx.x * EPB + ee;
        if (oe < B) out[oe] = o;
    }
}

extern "C" void kernel_launch(void* const* d_in, const int* in_sizes, int n_in,
                              void* d_out, int out_size, void* d_ws, size_t ws_size,
                              hipStream_t stream) {
    const float* x      = (const float*)d_in[0];
    const float* w_in   = (const float*)d_in[1];
    const float* b_in   = (const float*)d_in[2];
    const float* w_ih0  = (const float*)d_in[3];
    const float* w_hh0  = (const float*)d_in[4];
    const float* b_ih0  = (const float*)d_in[5];
    const float* b_hh0  = (const float*)d_in[6];
    const float* w_ih1  = (const float*)d_in[7];
    const float* w_hh1  = (const float*)d_in[8];
    const float* b_ih1  = (const float*)d_in[9];
    const float* b_hh1  = (const float*)d_in[10];
    const float* fc_h_w = (const float*)d_in[11];
    const float* fc_h_b = (const float*)d_in[12];
    const float* fc_o_w = (const float*)d_in[13];
    const float* fc_o_b = (const float*)d_in[14];

    const int B = out_size;                 // x is [B,T,1]
    const int T = in_sizes[0] / (B > 0 ? B : 1);
    const int grid = (B + EPB - 1) / EPB;   // 32 blocks at B=8192

    hipLaunchKernelGGL(lstm_pack, dim3(grid), dim3(WPB * 64), 0, stream,
                       x, w_in, b_in, w_ih0, w_hh0, b_ih0, b_hh0,
                       w_ih1, w_hh1, b_ih1, b_hh1, fc_h_w, fc_h_b,
                       fc_o_w, fc_o_b, (float*)d_out, B, T);
}

// Round 20
// 189.886 us; speedup vs baseline: 5.3921x; 5.3921x over previous
//
#include <hip/hip_runtime.h>
#include <math.h>

// LSTMLightweight on MI355X (R20 = R14 structure, f16 2-product MFMA).
//   x[B,T,1] -> linear_in(1->16)+ReLU -> LSTM0(16) -> LSTM1(16) -> fc(16->8)+ReLU -> fc(8->1)
// R19 lesson: 1024-thread blocks -> 64-VGPR target -> true spill (1024us);
// and with 512 total waves, total time = 256 x per-step wall regardless of
// wave packing. The lever is the per-step wall: ~1900 cyc of which ~1245 is
// VALU issue (~620 instr vs ~120 static) — unified-file pressure (R14 needs
// ~175 live vs 128 budget) parks ~50 values in AGPRs with copy traffic.
// R20: f16 with B-side-only split. f16 mantissa (11 bit) makes
//   Ahi*Bh + Ahi*Bl  capture B nearly exactly; only A's RTN error (~2^-12
// rel) remains -> predicted absmax ~1e-3 (<< 9.1e-3). Cuts A-frags 64->32
// regs and MFMAs 24->16/step -> live set ~140, only biases park.
// Layout identical to R11-R19 (C/D layout is dtype-independent; A/B frag =
// 8 elems/4 VGPRs for both bf16 and f16): K-permuted A so B is lane-local
// (k=8g+i -> W_ih[.][4g+i] | W_hh[.][4g+i-4]; D row=4*(lane>>4)+q, col=lane&15).
// L1(t) || L0(t+1) software pipeline (R14-proven, +10%).

#define L2E 1.4426950408889634f
#define EPB 16        // elements per wave (= MFMA N)

typedef _Float16 f16x8 __attribute__((ext_vector_type(8)));
typedef float    f32x4 __attribute__((ext_vector_type(4)));

__device__ __forceinline__ float sigm(float v) {
    return __builtin_amdgcn_rcpf(1.0f + __builtin_amdgcn_exp2f(-L2E * v));
}
__device__ __forceinline__ float tanh_(float v) {
    // tanh(v) = 1 - 2/(exp(2v)+1); saturates correctly at +-inf
    return 1.0f - 2.0f * __builtin_amdgcn_rcpf(1.0f + __builtin_amdgcn_exp2f((2.0f * L2E) * v));
}

// split a float into f16 hi (RTN cast) + f16 lo (residual; exact in f32)
#define SPLIT4(V, FH, FL)                                         \
    _Pragma("unroll")                                             \
    for (int i_ = 0; i_ < 4; ++i_) {                              \
        const _Float16 hh_ = (_Float16)V[i_];                     \
        FH[i_] = hh_;                                             \
        FL[i_] = (_Float16)(V[i_] - (float)hh_);                  \
    }

__device__ __forceinline__ f16x8 mk8(const _Float16* a, const _Float16* b) {
    f16x8 r;
    #pragma unroll
    for (int i = 0; i < 4; ++i) { r[i] = a[i]; r[4 + i] = b[i]; }
    return r;
}

// one layer's gates: acc[m] = bias[m] + Ahi·Bl + Ahi·Bh   (2 MFMAs/tile)
#define GATES16(ACC, AHI, BIAS, BH, BL)                                               \
    _Pragma("unroll")                                                                 \
    for (int m = 0; m < 4; ++m) {                                                     \
        ACC[m] = BIAS[m];                                                             \
        ACC[m] = __builtin_amdgcn_mfma_f32_16x16x32_f16(AHI[m], BL, ACC[m], 0, 0, 0); \
        ACC[m] = __builtin_amdgcn_mfma_f32_16x16x32_f16(AHI[m], BH, ACC[m], 0, 0, 0); \
    }

// combine: i,f,g,o -> c,h (per q); writes HV[4] and updates CC[4]
#define COMBINE(ACC, CC, HV)                                                          \
    _Pragma("unroll")                                                                 \
    for (int q = 0; q < 4; ++q) {                                                     \
        const float ig_ = sigm(ACC[0][q]);                                            \
        const float fg_ = sigm(ACC[1][q]);                                            \
        const float gv_ = tanh_(ACC[2][q]);                                           \
        const float og_ = sigm(ACC[3][q]);                                            \
        CC[q] = fmaf(fg_, CC[q], ig_ * gv_);                                          \
        HV[q] = og_ * tanh_(CC[q]);                                                   \
    }

__global__ __launch_bounds__(64) void lstm_f16(
    const float* __restrict__ x,
    const float* __restrict__ w_in, const float* __restrict__ b_in,
    const float* __restrict__ w_ih0, const float* __restrict__ w_hh0,
    const float* __restrict__ b_ih0, const float* __restrict__ b_hh0,
    const float* __restrict__ w_ih1, const float* __restrict__ w_hh1,
    const float* __restrict__ b_ih1, const float* __restrict__ b_hh1,
    const float* __restrict__ fc_h_w, const float* __restrict__ fc_h_b,
    const float* __restrict__ fc_o_w, const float* __restrict__ fc_o_b,
    float* __restrict__ out, int B, int T)
{
    const int lane = threadIdx.x;        // 0..63
    const int e    = lane & 15;          // element column (= A row within tile)
    const int g    = lane >> 4;          // k-group / D-row group
    const int base = blockIdx.x * EPB;
    int rowe = base + e; if (rowe >= B) rowe = B - 1;

    __shared__ float htab[EPB][16];      // head exchange only

    // ---- A-fragments (f16 RTN, single plane), K-permuted ----
    f16x8 a0[4], a1[4];
    f32x4 bias0[4], bias1[4];
    #pragma unroll
    for (int m = 0; m < 4; ++m) {
        const int r = 16 * m + e;
        #pragma unroll
        for (int i = 0; i < 8; ++i) {
            const float w0 = (i < 4) ? w_ih0[r * 16 + 4 * g + i]
                                     : w_hh0[r * 16 + 4 * g + (i - 4)];
            const float w1 = (i < 4) ? w_ih1[r * 16 + 4 * g + i]
                                     : w_hh1[r * 16 + 4 * g + (i - 4)];
            a0[m][i] = (_Float16)w0;
            a1[m][i] = (_Float16)w1;
        }
        const int rd = 16 * m + 4 * g;
        #pragma unroll
        for (int q = 0; q < 4; ++q) {
            bias0[m][q] = b_ih0[rd + q] + b_hh0[rd + q];
            bias1[m][q] = b_ih1[rd + q] + b_hh1[rd + q];
        }
    }
    float winq[4], binq[4];
    #pragma unroll
    for (int q = 0; q < 4; ++q) { winq[q] = w_in[4 * g + q]; binq[q] = b_in[4 * g + q]; }

    // ---- state: c in f32; h kept as f16 hi/lo element arrays ----
    float c0[4] = {0.f, 0.f, 0.f, 0.f};
    float c1[4] = {0.f, 0.f, 0.f, 0.f};
    float h1v[4] = {0.f, 0.f, 0.f, 0.f};
    _Float16 h0h[4], h0l[4], h1h[4], h1l[4];
    #pragma unroll
    for (int q = 0; q < 4; ++q) { h1h[q] = (_Float16)0.f; h1l[q] = (_Float16)0.f; }

    const float* xrow = x + (size_t)rowe * T;

    // ---- prologue: L0 at t=0 (h0_{-1}=0) ----
    {
        const float xv = xrow[0];
        float xq[4];
        #pragma unroll
        for (int q = 0; q < 4; ++q) xq[q] = fmaxf(fmaf(xv, winq[q], binq[q]), 0.0f);
        _Float16 xh[4], xl[4], zh[4];
        SPLIT4(xq, xh, xl);
        #pragma unroll
        for (int q = 0; q < 4; ++q) zh[q] = (_Float16)0.f;
        const f16x8 Bh = mk8(xh, zh);
        const f16x8 Bl = mk8(xl, zh);
        f32x4 acc[4];
        GATES16(acc, a0, bias0, Bh, Bl);
        float h0v[4];
        COMBINE(acc, c0, h0v);
        SPLIT4(h0v, h0h, h0l);
    }

    float xv1 = xrow[(T > 1) ? 1 : 0];               // x(t+1) for the loop

    // ---- steady state: iteration t does L1(t) || L0(t+1) (independent) ----
    for (int t = 0; t < T - 1; ++t) {
        const int tn = (t + 2 < T) ? (t + 2) : (T - 1);
        const float xn = xrow[tn];                   // prefetch x(t+2)

        float xq[4];
        #pragma unroll
        for (int q = 0; q < 4; ++q) xq[q] = fmaxf(fmaf(xv1, winq[q], binq[q]), 0.0f);
        _Float16 xh[4], xl[4];
        SPLIT4(xq, xh, xl);

        // B-frags (all from pre-update h splits)
        const f16x8 B0h = mk8(xh, h0h);              // [xi(t+1); h0(t)]
        const f16x8 B0l = mk8(xl, h0l);
        const f16x8 B1h = mk8(h0h, h1h);             // [h0(t); h1(t-1)]
        const f16x8 B1l = mk8(h0l, h1l);

        f32x4 acc0[4], acc1[4];
        GATES16(acc0, a0, bias0, B0h, B0l);          // L0(t+1)
        GATES16(acc1, a1, bias1, B1h, B1l);          // L1(t)

        float h0v[4];
        COMBINE(acc0, c0, h0v);                      // h0(t+1)
        COMBINE(acc1, c1, h1v);                      // h1(t)

        SPLIT4(h0v, h0h, h0l);
        SPLIT4(h1v, h1h, h1l);
        xv1 = xn;
    }

    // ---- epilogue: L1(T-1) from h0(T-1), h1(T-2) ----
    {
        const f16x8 Bh = mk8(h0h, h1h);
        const f16x8 Bl = mk8(h0l, h1l);
        f32x4 acc[4];
        GATES16(acc, a1, bias1, Bh, Bl);
        COMBINE(acc, c1, h1v);                       // final h1
    }

    // ---- head: fc_h (16->8) + ReLU, fc_o (8->1) ----
    *(float4*)&htab[e][4 * g] = make_float4(h1v[0], h1v[1], h1v[2], h1v[3]);
    __syncthreads();
    if (lane < EPB) {
        const int ee = lane;
        float hv[16];
        #pragma unroll
        for (int k = 0; k < 16; ++k) hv[k] = htab[ee][k];
        float z[8];
        #pragma unroll
        for (int p = 0; p < 8; ++p) {
            float acc = fc_h_b[p];
            #pragma unroll
            for (int k = 0; k < 16; ++k) acc = fmaf(fc_h_w[p * 16 + k], hv[k], acc);
            z[p] = fmaxf(acc, 0.0f);
        }
        float o = fc_o_b[0];
        #pragma unroll
        for (int p = 0; p < 8; ++p) o = fmaf(fc_o_w[p], z[p], o);
        if (base + ee < B) out[base + ee] = o;
    }
}

extern "C" void kernel_launch(void* const* d_in, const int* in_sizes, int n_in,
                              void* d_out, int out_size, void* d_ws, size_t ws_size,
                              hipStream_t stream) {
    const float* x      = (const float*)d_in[0];
    const float* w_in   = (const float*)d_in[1];
    const float* b_in   = (const float*)d_in[2];
    const float* w_ih0  = (const float*)d_in[3];
    const float* w_hh0  = (const float*)d_in[4];
    const float* b_ih0  = (const float*)d_in[5];
    const float* b_hh0  = (const float*)d_in[6];
    const float* w_ih1  = (const float*)d_in[7];
    const float* w_hh1  = (const float*)d_in[8];
    const float* b_ih1  = (const float*)d_in[9];
    const float* b_hh1  = (const float*)d_in[10];
    const float* fc_h_w = (const float*)d_in[11];
    const float* fc_h_b = (const float*)d_in[12];
    const float* fc_o_w = (const float*)d_in[13];
    const float* fc_o_b = (const float*)d_in[14];

    const int B = out_size;                 // x is [B,T,1]
    const int T = in_sizes[0] / (B > 0 ? B : 1);
    const int grid = (B + EPB - 1) / EPB;   // 512 blocks at B=8192

    hipLaunchKernelGGL(lstm_f16, dim3(grid), dim3(64), 0, stream,
                       x, w_in, b_in, w_ih0, w_hh0, b_ih0, b_hh0,
                       w_ih1, w_hh1, b_ih1, b_hh1, fc_h_w, fc_h_b,
                       fc_o_w, fc_o_b, (float*)d_out, B, T);
}